// Round 1
// baseline (1809.577 us; speedup 1.0000x reference)
//
#include <hip/hip_runtime.h>
#include <hip/hip_fp16.h>

// FixedFreqModel: B=512, L=2048, M=256, H=64, VOCAB=64, READ_FREQ=16.
// R13 = R12 + latency/residency fixes (bit-exact math, scheduling only):
//  - amdgpu_waves_per_eu(1,1): full 512-VGPR budget (only 2 waves/CU exist).
//  - W_hh (96 u32) AND WR (96 u32) held in VGPRs, pinned with asm so the
//    compiler cannot demote them to AGPR-spill / re-loads (R12 showed
//    VGPR_Count=84, impossible if weights were resident).
//  - WR2p loaded once before the main loop (was re-read every chunk).
//  - Token int4s for chunk c+1 prefetched during chunk c; G rows for GRU
//    group g+1 prefetched at top of group g (group 0's at chunk top, hidden
//    under attention). Explicit register rotation, all indices static.

#define B_ 512
#define L_ 2048
#define M_ 256
#define H_ 64
#define C_ 128
#define F_ 16

typedef float v2f __attribute__((ext_vector_type(2)));
typedef _Float16 h2v __attribute__((ext_vector_type(2)));

#if __has_builtin(__builtin_amdgcn_fdot2)
__device__ __forceinline__ float FDOT2(h2v a, h2v b, float c) {
    return __builtin_amdgcn_fdot2(a, b, c, false);
}
#else
__device__ __forceinline__ float FDOT2(h2v a, h2v b, float c) {
    return c + (float)a[0]*(float)b[0] + (float)a[1]*(float)b[1];
}
#endif

__device__ __forceinline__ h2v bch(unsigned u) { return __builtin_bit_cast(h2v, u); }
__device__ __forceinline__ unsigned rl_u(unsigned v, int lane) {
    return (unsigned)__builtin_amdgcn_readlane((int)v, lane);
}
__device__ __forceinline__ float rl(float v, int lane) {
    return __int_as_float(__builtin_amdgcn_readlane(__float_as_int(v), lane));
}
// pack (mine, neighbor) -> half2 in lane order (even idx first)
__device__ __forceinline__ unsigned packpair(float mine, float other, bool odd) {
    float lo = odd ? other : mine;
    float hi = odd ? mine : other;
    auto r = __builtin_amdgcn_cvt_pkrtz(lo, hi);   // __fp16 ext_vector(2)
    return __builtin_bit_cast(unsigned, r);
}
__device__ __forceinline__ float dot4(float4 a, float4 b) {
    return a.x*b.x + a.y*b.y + a.z*b.z + a.w*b.w;
}
__device__ __forceinline__ void cvt2v(uint2 raw, v2f& lo, v2f& hi) {
    __half2* hp = (__half2*)&raw;
    float2 a = __half22float2(hp[0]);
    float2 b = __half22float2(hp[1]);
    lo[0] = a.x; lo[1] = a.y; hi[0] = b.x; hi[1] = b.y;
}
__device__ __forceinline__ float fast_rcp(float x) { return __builtin_amdgcn_rcpf(x); }
__device__ __forceinline__ float sigm(float x) { return fast_rcp(1.f + __expf(-x)); }
__device__ __forceinline__ float tanh_f(float x) {
    float e2 = __expf(-2.f * fabsf(x));
    return copysignf((1.f - e2) * fast_rcp(1.f + e2), x);
}
__device__ __forceinline__ unsigned h2rn(float a, float b) {
    __half2 h = __floats2half2_rn(a, b);
    return __builtin_bit_cast(unsigned, h);
}

// workspace offsets (bytes)
#define WS_KT    0u            // kT2: 512 * 8192 u32 = 16 MB  [b][hh2][m]
#define WS_V     16777216u     // v fp16: 16 MB [b][m][o]
#define WS_G     33554432u     // 64*192 fp32 = 48 KB
#define WS_WPHH  33603584u     // 6144 u32 = 24 KB  [(k2*3+g)*64+j]
#define WS_WR    33628160u     // 6144 u32 = 24 KB
#define WS_QP    33652736u     // 2048 u32 = 8 KB   [k2*64+j]
#define WS_KWP   33660928u     // 1024 float4 = 16 KB
#define WS_VWP   33677312u     // 16 KB

// dynamic LDS layout (bytes)
#define S_KT   0u        // 32768 : kT2 u32 [hh2=32][m=256]  (uint4 per (hh2, 4m))
#define S_V    32768u    // 32768 : v half [m][o]
#define S_QP   65536u    // 8192  : QP2 u32 [k2=32][j=64]
#define S_P    73728u    // 1024  : float4 p_s[64]
#define SMEM_BYTES 74752u

// ---------------- pack weights -----------------------------------------------
__global__ void pack_weights(const float* __restrict__ w_ih,
                             const float* __restrict__ w_hh,
                             const float* __restrict__ qw,
                             const float* __restrict__ kw,
                             const float* __restrict__ vw,
                             unsigned* __restrict__ WPhh2,
                             unsigned* __restrict__ WR2p,
                             unsigned* __restrict__ QP2,
                             float4* __restrict__ KWP,
                             float4* __restrict__ VWP)
{
    int idx = blockIdx.x * 256 + threadIdx.x;
    if (idx < 6144) {                        // WPhh2[(k2*3+g)*64+j]
        int j = idx & 63, t = idx >> 6, g = t % 3, k2 = t / 3;
        const float* s = w_hh + (g*64 + j)*64 + 2*k2;
        WPhh2[idx] = h2rn(s[0], s[1]);
    } else if (idx < 12288) {                // WR2p: retrieved half of w_ih
        int i = idx - 6144;
        int j = i & 63, t = i >> 6, g = t % 3, k2 = t / 3;
        const float* s = w_ih + (g*64 + j)*128 + 64 + 2*k2;
        WR2p[i] = h2rn(s[0], s[1]);
    } else if (idx < 14336) {                // QP2[k2*64+j]
        int i = idx - 12288;
        int j = i & 63, k2 = i >> 6;
        const float* s = qw + j*64 + 2*k2;
        QP2[i] = h2rn(s[0], s[1]);
    } else if (idx < 15360) {
        int i = idx - 14336;
        int j = i & 63, k4 = i >> 6;
        const float* s = kw + j*64 + 4*k4;
        KWP[i] = make_float4(s[0], s[1], s[2], s[3]);
    } else if (idx < 16384) {
        int i = idx - 15360;
        int j = i & 63, k4 = i >> 6;
        const float* s = vw + j*64 + 4*k4;
        VWP[i] = make_float4(s[0], s[1], s[2], s[3]);
    }
}

// ---------------- G[v][o] = sum_k embed[v][k]*w_ih[o][k] + b_ih[o] ----------
__global__ __launch_bounds__(64) void build_G(const float* __restrict__ embed_w,
                                              const float* __restrict__ w_ih,
                                              const float* __restrict__ b_ih,
                                              float* __restrict__ G)
{
    int v = blockIdx.x, j = threadIdx.x;
    __shared__ float e_s[64];
    e_s[j] = embed_w[v*64 + j];
    __syncthreads();
    float a0 = b_ih[j], a1 = b_ih[64 + j], a2 = b_ih[128 + j];
    for (int k = 0; k < 64; ++k) {
        float e = e_s[k];
        a0 += e * w_ih[j*128 + k];
        a1 += e * w_ih[(64 + j)*128 + k];
        a2 += e * w_ih[(128 + j)*128 + k];
    }
    G[v*192 + j]       = a0;
    G[v*192 + 64 + j]  = a1;
    G[v*192 + 128 + j] = a2;
}

// ---------------- k/v precompute (kT hh-pair-interleaved u32; v fp16) --------
__global__ __launch_bounds__(256) void compute_kv(const float* __restrict__ memory,
                                                  const float* __restrict__ key_b,
                                                  const float* __restrict__ val_b,
                                                  const float4* __restrict__ KWP,
                                                  const float4* __restrict__ VWP,
                                                  unsigned* __restrict__ kT2,
                                                  __half* __restrict__ v_h)
{
    int wid = threadIdx.x >> 6;
    int o   = threadIdx.x & 63;
    int row = blockIdx.x * 4 + wid;          // row = b*256 + m
    int b = row >> 8, m = row & 255;
    __shared__ __align__(16) float mem_s[4][64];
    mem_s[wid][o] = memory[(size_t)row * 64 + o];
    __syncthreads();
    float ak = key_b[o], av = val_b[o];
    const float4* m4 = (const float4*)mem_s[wid];
#pragma unroll
    for (int k4 = 0; k4 < 16; ++k4) {
        float4 mm = m4[k4];
        ak += dot4(mm, KWP[k4*64 + o]);
        av += dot4(mm, VWP[k4*64 + o]);
    }
    float nb = __shfl_xor(ak, 1);            // k[o^1][m]
    if ((o & 1) == 0)                        // pair (k[o][m], k[o+1][m])
        kT2[((size_t)b*32 + (o >> 1))*256 + m] = h2rn(ak, nb);
    v_h[(size_t)row*64 + o] = __float2half(av);
}

// one GRU step: h broadcast as half2 via readlane; dot2 matvec; no LDS
#define GRU_STEP(cg0, cg1, cg2) do {                                        \
    float gr = (cg0) + RrB, gz = (cg1) + RzB, gn = bhn;                     \
    _Pragma("unroll")                                                       \
    for (int kp = 0; kp < 32; ++kp) {                                       \
        h2v hhp = bch(rl_u(hpu, 2*kp));                                     \
        gr = FDOT2(hhp, bch(wru[kp]), gr);                                  \
        gz = FDOT2(hhp, bch(wzu[kp]), gz);                                  \
        gn = FDOT2(hhp, bch(wnu[kp]), gn);                                  \
    }                                                                       \
    float r_ = sigm(gr);                                                    \
    float z_ = sigm(gz);                                                    \
    float n_ = tanh_f(((cg2) + Rn) + r_ * gn);                              \
    h = fmaf(z_, h - n_, n_);                                               \
    float hx_ = __shfl_xor(h, 1);                                           \
    hpu = packpair(h, hx_, odd);                                            \
} while (0)

// ---------------- main recurrent kernel: 1 wave per batch element ------------
__global__ __launch_bounds__(64)
__attribute__((amdgpu_waves_per_eu(1, 1)))
void recurrent_main(
    const int*   __restrict__ seq,
    const float* __restrict__ b_hh,
    const float* __restrict__ query_b,
    const float* __restrict__ head_w,
    const float* __restrict__ head_b,
    const unsigned* __restrict__ kT2g,
    const __half* __restrict__ v_h,
    const float* __restrict__ G,
    const unsigned* __restrict__ WPhh2,
    const unsigned* __restrict__ WR2p,
    const unsigned* __restrict__ QP2g,
    float* __restrict__ out)
{
    const int b = blockIdx.x;
    const int j = threadIdx.x;
    const bool odd = (j & 1);

    extern __shared__ __align__(16) char smem[];
    const uint4* kT2_lds = (const uint4*)(smem + S_KT);  // [hh2*64 + j]: 4 m-pairs
    const uint2* v_u2    = (const uint2*)(smem + S_V);   // [m*16 + o4]
    const unsigned* qp2  = (const unsigned*)(smem + S_QP); // [k2*64 + j]
    float4* p_s4  = (float4*)(smem + S_P);

    // ---- stage kT2, v, QP2 into LDS once ----
    {
        const uint4* kTg = (const uint4*)(kT2g + (size_t)b * 8192);
        const uint4* vg  = (const uint4*)(v_h  + (size_t)b * 16384);
        uint4* kTls = (uint4*)(smem + S_KT);
        uint4* vls  = (uint4*)(smem + S_V);
#pragma unroll
        for (int i = 0; i < 32; ++i) {
            kTls[i*64 + j] = kTg[i*64 + j];
            vls[i*64 + j]  = vg[i*64 + j];
        }
        const uint4* qpg = (const uint4*)QP2g;
        uint4* qls = (uint4*)(smem + S_QP);
#pragma unroll
        for (int i = 0; i < 8; ++i) qls[i*64 + j] = qpg[i*64 + j];
    }

    // ---- W_hh and WR in registers as half2 words: 192 VGPRs, pinned ----
    unsigned wru[32], wzu[32], wnu[32];
    unsigned rru[32], rzu[32], rnu[32];
#pragma unroll
    for (int k2 = 0; k2 < 32; ++k2) {
        wru[k2] = WPhh2[(k2*3 + 0)*64 + j];
        wzu[k2] = WPhh2[(k2*3 + 1)*64 + j];
        wnu[k2] = WPhh2[(k2*3 + 2)*64 + j];
        rru[k2] = WR2p[(k2*3 + 0)*64 + j];
        rzu[k2] = WR2p[(k2*3 + 1)*64 + j];
        rnu[k2] = WR2p[(k2*3 + 2)*64 + j];
    }
    // pin: forbid AGPR-demotion / re-load of the weight words (one-time wait)
#pragma unroll
    for (int k2 = 0; k2 < 32; ++k2) {
        asm volatile("" : "+v"(wru[k2]), "+v"(wzu[k2]), "+v"(wnu[k2]),
                          "+v"(rru[k2]), "+v"(rzu[k2]), "+v"(rnu[k2]));
    }

    float h = 0.f;                       // lane j owns h[j]; never leaves regs
    unsigned hpu = 0u;                   // packed (h[2t], h[2t+1]) fp16 pair
    const float bhr = b_hh[j], bhz = b_hh[64 + j], bhn = b_hh[128 + j];
    const float qb  = query_b[j];

    const int* seqb = seq + (size_t)b * L_;
    const int4* sp4 = (const int4*)seqb;
    const int o4 = j & 15;        // h-quad owned in v-loop
    const int mg = j >> 4;        // m-group 0..3
    __builtin_amdgcn_wave_barrier();

    // tokens for chunk 0 (subsequent chunks prefetched a chunk ahead)
    int4 t0 = sp4[0], t1 = sp4[1], t2 = sp4[2], t3 = sp4[3];
    // double-buffered G rows for the 4-token GRU group in flight
    float nA0, nA1, nA2, nB0, nB1, nB2, nC0, nC1, nC2, nD0, nD1, nD2;

    for (int c = 0; c < C_; ++c) {
        // ---- prefetch G rows for GRU group 0 (hidden under attention) ----
        {
            const float* PA = G + t0.x*192;
            const float* PB = G + t0.y*192;
            const float* PC = G + t0.z*192;
            const float* PD = G + t0.w*192;
            nA0 = PA[j]; nA1 = PA[64+j]; nA2 = PA[128+j];
            nB0 = PB[j]; nB1 = PB[64+j]; nB2 = PB[128+j];
            nC0 = PC[j]; nC1 = PC[64+j]; nC2 = PC[128+j];
            nD0 = PD[j]; nD1 = PD[64+j]; nD2 = PD[128+j];
        }

        // ---- q[j] = qb + sum_k h[k]*Wq[j][k]  (dot2: h pairs + QP2 LDS) ----
        float q = qb;
#pragma unroll 8
        for (int k2 = 0; k2 < 32; ++k2) {
            h2v pp = bch(qp2[k2*64 + j]);
            h2v hh = bch(rl_u(hpu, 2*k2));
            q = FDOT2(hh, pp, q);
        }

        // ---- scores: lane j owns m = 4j..4j+3 (dot2 over hh-pairs) ----
        float qx = __shfl_xor(q, 1);
        unsigned qpu = packpair(q, qx, odd);
        float s0 = 0.f, s1 = 0.f, s2 = 0.f, s3 = 0.f;
#pragma unroll 8
        for (int t = 0; t < 32; ++t) {
            h2v qq = bch(rl_u(qpu, 2*t));
            uint4 kk = kT2_lds[t*64 + j];
            s0 = FDOT2(bch(kk.x), qq, s0);
            s1 = FDOT2(bch(kk.y), qq, s1);
            s2 = FDOT2(bch(kk.z), qq, s2);
            s3 = FDOT2(bch(kk.w), qq, s3);
        }
        const float scale = 0.125f;
        // softmax, no max-sub (|s| small), rcp not div
        float4 p;
        p.x = __expf(s0*scale); p.y = __expf(s1*scale);
        p.z = __expf(s2*scale); p.w = __expf(s3*scale);
        float sum = (p.x + p.y) + (p.z + p.w);
#pragma unroll
        for (int o = 32; o > 0; o >>= 1) sum += __shfl_xor(sum, o);
        float inv = fast_rcp(sum);
        p_s4[j] = p;
        __builtin_amdgcn_wave_barrier();

        // ---- retrieved: lane (mg,o4) over m = 4i+mg (fp16 v, pk fp32) ----
        const float* ps = (const float*)p_s4;
        v2f aA0 = {0.f,0.f}, aB0 = {0.f,0.f};
        v2f aA1 = {0.f,0.f}, aB1 = {0.f,0.f};
#pragma unroll 4
        for (int i = 0; i < 64; i += 2) {
            int m0 = 4*i + mg, m1 = 4*(i + 1) + mg;
            float p0 = ps[m0], p1 = ps[m1];
            v2f v0l, v0h, v1l, v1h;
            cvt2v(v_u2[m0*16 + o4], v0l, v0h);
            cvt2v(v_u2[m1*16 + o4], v1l, v1h);
            aA0 += v0l * p0; aB0 += v0h * p0;
            aA1 += v1l * p1; aB1 += v1h * p1;
        }
        float4 acc;
        acc.x = (aA0[0] + aA1[0]) * inv;
        acc.y = (aA0[1] + aA1[1]) * inv;
        acc.z = (aB0[0] + aB1[0]) * inv;
        acc.w = (aB0[1] + aB1[1]) * inv;
#pragma unroll
        for (int o = 16; o <= 32; o <<= 1) {
            acc.x += __shfl_xor(acc.x, o);
            acc.y += __shfl_xor(acc.y, o);
            acc.z += __shfl_xor(acc.z, o);
            acc.w += __shfl_xor(acc.w, o);
        }
        // lane t (and t+16/32/48) holds ret[4t..4t+3] in acc

        // ---- R matvec: ret packed fp16 pairs + WR words in VGPRs (dot2) ----
        unsigned rp0 = packpair(acc.x, acc.y, false);  // (ret[4t], ret[4t+1])
        unsigned rp1 = packpair(acc.z, acc.w, false);  // (ret[4t+2], ret[4t+3])
        float Rr = 0.f, Rz = 0.f, Rn = 0.f;
#pragma unroll 8
        for (int k2 = 0; k2 < 32; ++k2) {
            unsigned rsel = (k2 & 1) ? rp1 : rp0;
            h2v rr = bch(rl_u(rsel, k2 >> 1));
            Rr = FDOT2(rr, bch(rru[k2]), Rr);
            Rz = FDOT2(rr, bch(rzu[k2]), Rz);
            Rn = FDOT2(rr, bch(rnu[k2]), Rn);
        }
        const float RrB = Rr + bhr, RzB = Rz + bhz;

        // ---- rotation regs for within-chunk group prefetch, then prefetch
        //      NEXT chunk's tokens (hidden under the 16 GRU steps) ----
        int4 r1 = t1, r2 = t2, r3 = t3;
        {
            int off = (c + 1 < C_) ? (c + 1) * 4 : 0;  // int4 units
            t0 = sp4[off + 0]; t1 = sp4[off + 1];
            t2 = sp4[off + 2]; t3 = sp4[off + 3];
        }

        // ---- 16 GRU steps: 4 dynamic groups x 4 unrolled (I-cache OK).
        //      Group g+1's G rows prefetched during group g's steps. ----
#pragma unroll 1
        for (int g = 0; g < 4; ++g) {
            float cA0=nA0, cA1=nA1, cA2=nA2;
            float cB0=nB0, cB1=nB1, cB2=nB2;
            float cC0=nC0, cC1=nC1, cC2=nC2;
            float cD0=nD0, cD1=nD1, cD2=nD2;
            const float* PA = G + r1.x*192;
            const float* PB = G + r1.y*192;
            const float* PC = G + r1.z*192;
            const float* PD = G + r1.w*192;
            r1 = r2; r2 = r3;
            nA0 = PA[j]; nA1 = PA[64+j]; nA2 = PA[128+j];
            nB0 = PB[j]; nB1 = PB[64+j]; nB2 = PB[128+j];
            nC0 = PC[j]; nC1 = PC[64+j]; nC2 = PC[128+j];
            nD0 = PD[j]; nD1 = PD[64+j]; nD2 = PD[128+j];

            GRU_STEP(cA0, cA1, cA2);
            GRU_STEP(cB0, cB1, cB2);
            GRU_STEP(cC0, cC1, cC2);
            GRU_STEP(cD0, cD1, cD2);
        }
    }

    // ---- head: out[b][j] = head_b[j] + sum_k h[k]*head_w[j][k] (fp32) ----
    float o = head_b[j];
#pragma unroll
    for (int k4 = 0; k4 < 16; ++k4) {
        float h0 = rl(h, 4*k4+0), h1 = rl(h, 4*k4+1);
        float h2 = rl(h, 4*k4+2), h3 = rl(h, 4*k4+3);
        const float* hw = head_w + j*64 + 4*k4;
        o += h0*hw[0] + h1*hw[1] + h2*hw[2] + h3*hw[3];
    }
    out[(size_t)b*64 + j] = o;
}

extern "C" void kernel_launch(void* const* d_in, const int* in_sizes, int n_in,
                              void* d_out, int out_size, void* d_ws, size_t ws_size,
                              hipStream_t stream) {
    const int*   seq      = (const int*)  d_in[0];
    const float* memory   = (const float*)d_in[1];
    const float* embed_w  = (const float*)d_in[2];
    const float* w_ih     = (const float*)d_in[3];
    const float* w_hh     = (const float*)d_in[4];
    const float* b_ih     = (const float*)d_in[5];
    const float* b_hh     = (const float*)d_in[6];
    const float* key_w    = (const float*)d_in[7];
    const float* key_b    = (const float*)d_in[8];
    const float* val_w    = (const float*)d_in[9];
    const float* val_b    = (const float*)d_in[10];
    const float* query_w  = (const float*)d_in[11];
    const float* query_b  = (const float*)d_in[12];
    const float* head_w   = (const float*)d_in[13];
    const float* head_b   = (const float*)d_in[14];

    char* ws = (char*)d_ws;
    unsigned* kT2  = (unsigned*)(ws + WS_KT);
    __half*   v_h  = (__half*)  (ws + WS_V);
    float*    G    = (float*)   (ws + WS_G);
    unsigned* WPhh2 = (unsigned*)(ws + WS_WPHH);
    unsigned* WR2p  = (unsigned*)(ws + WS_WR);
    unsigned* QP2   = (unsigned*)(ws + WS_QP);
    float4*   KWP   = (float4*)  (ws + WS_KWP);
    float4*   VWP   = (float4*)  (ws + WS_VWP);

    (void)hipFuncSetAttribute((const void*)recurrent_main,
                              hipFuncAttributeMaxDynamicSharedMemorySize,
                              (int)SMEM_BYTES);

    pack_weights<<<64, 256, 0, stream>>>(w_ih, w_hh, query_w, key_w, val_w,
                                         WPhh2, WR2p, QP2, KWP, VWP);
    build_G<<<64, 64, 0, stream>>>(embed_w, w_ih, b_ih, G);
    compute_kv<<<(B_*M_)/4, 256, 0, stream>>>(memory, key_b, val_b, KWP, VWP, kT2, v_h);
    recurrent_main<<<B_, 64, SMEM_BYTES, stream>>>(seq, b_hh, query_b, head_w, head_b,
                                                   kT2, v_h, G, WPhh2, WR2p, QP2,
                                                   (float*)d_out);
}

// Round 3
// 1755.690 us; speedup vs baseline: 1.0307x; 1.0307x over previous
//
#include <hip/hip_runtime.h>
#include <hip/hip_fp16.h>

// FixedFreqModel: B=512, L=2048, M=256, H=64, VOCAB=64, READ_FREQ=16.
// R15 = R14 resubmitted verbatim (R14's bench was an infra failure: container
// acquisition failed twice; no compile/correctness signal was produced).
// R14 = R12 (best known, 1380us) + exactly two latency-hiding edits:
//  1. Token/G software pipeline: GRU group g prefetches group g+1's G rows
//     (g=3 prefetches next chunk's group 0, hiding under 4 GRU steps + the
//     whole next attention phase). Tokens for chunk c+1 loaded during c.
//     Steady-state 4-deep int4 queue, all indices static.
//  2. Softmax reorder: p written to LDS before the 6-shfl sum-reduce, so the
//     reduce chain overlaps the v-loop's LDS reads (inv used only at end).
// NO register pins, NO waves_per_eu: R13 showed W_hh/WR already live in
// AGPRs (unified file, dot2 reads AGPR directly); pinning them into arch
// VGPRs caused accvgpr churn and a 17% regression.

#define B_ 512
#define L_ 2048
#define M_ 256
#define H_ 64
#define C_ 128
#define F_ 16

typedef float v2f __attribute__((ext_vector_type(2)));
typedef _Float16 h2v __attribute__((ext_vector_type(2)));

#if __has_builtin(__builtin_amdgcn_fdot2)
__device__ __forceinline__ float FDOT2(h2v a, h2v b, float c) {
    return __builtin_amdgcn_fdot2(a, b, c, false);
}
#else
__device__ __forceinline__ float FDOT2(h2v a, h2v b, float c) {
    return c + (float)a[0]*(float)b[0] + (float)a[1]*(float)b[1];
}
#endif

__device__ __forceinline__ h2v bch(unsigned u) { return __builtin_bit_cast(h2v, u); }
__device__ __forceinline__ unsigned rl_u(unsigned v, int lane) {
    return (unsigned)__builtin_amdgcn_readlane((int)v, lane);
}
__device__ __forceinline__ float rl(float v, int lane) {
    return __int_as_float(__builtin_amdgcn_readlane(__float_as_int(v), lane));
}
// pack (mine, neighbor) -> half2 in lane order (even idx first)
__device__ __forceinline__ unsigned packpair(float mine, float other, bool odd) {
    float lo = odd ? other : mine;
    float hi = odd ? mine : other;
    auto r = __builtin_amdgcn_cvt_pkrtz(lo, hi);   // __fp16 ext_vector(2)
    return __builtin_bit_cast(unsigned, r);
}
__device__ __forceinline__ float dot4(float4 a, float4 b) {
    return a.x*b.x + a.y*b.y + a.z*b.z + a.w*b.w;
}
__device__ __forceinline__ void cvt2v(uint2 raw, v2f& lo, v2f& hi) {
    __half2* hp = (__half2*)&raw;
    float2 a = __half22float2(hp[0]);
    float2 b = __half22float2(hp[1]);
    lo[0] = a.x; lo[1] = a.y; hi[0] = b.x; hi[1] = b.y;
}
__device__ __forceinline__ float fast_rcp(float x) { return __builtin_amdgcn_rcpf(x); }
__device__ __forceinline__ float sigm(float x) { return fast_rcp(1.f + __expf(-x)); }
__device__ __forceinline__ float tanh_f(float x) {
    float e2 = __expf(-2.f * fabsf(x));
    return copysignf((1.f - e2) * fast_rcp(1.f + e2), x);
}
__device__ __forceinline__ unsigned h2rn(float a, float b) {
    __half2 h = __floats2half2_rn(a, b);
    return __builtin_bit_cast(unsigned, h);
}

// workspace offsets (bytes)
#define WS_KT    0u            // kT2: 512 * 8192 u32 = 16 MB  [b][hh2][m]
#define WS_V     16777216u     // v fp16: 16 MB [b][m][o]
#define WS_G     33554432u     // 64*192 fp32 = 48 KB
#define WS_WPHH  33603584u     // 6144 u32 = 24 KB  [(k2*3+g)*64+j]
#define WS_WR    33628160u     // 6144 u32 = 24 KB
#define WS_QP    33652736u     // 2048 u32 = 8 KB   [k2*64+j]
#define WS_KWP   33660928u     // 1024 float4 = 16 KB
#define WS_VWP   33677312u     // 16 KB

// dynamic LDS layout (bytes)
#define S_KT   0u        // 32768 : kT2 u32 [hh2=32][m=256]  (uint4 per (hh2, 4m))
#define S_V    32768u    // 32768 : v half [m][o]
#define S_QP   65536u    // 8192  : QP2 u32 [k2=32][j=64]
#define S_P    73728u    // 1024  : float4 p_s[64]
#define SMEM_BYTES 74752u

// ---------------- pack weights -----------------------------------------------
__global__ void pack_weights(const float* __restrict__ w_ih,
                             const float* __restrict__ w_hh,
                             const float* __restrict__ qw,
                             const float* __restrict__ kw,
                             const float* __restrict__ vw,
                             unsigned* __restrict__ WPhh2,
                             unsigned* __restrict__ WR2p,
                             unsigned* __restrict__ QP2,
                             float4* __restrict__ KWP,
                             float4* __restrict__ VWP)
{
    int idx = blockIdx.x * 256 + threadIdx.x;
    if (idx < 6144) {                        // WPhh2[(k2*3+g)*64+j]
        int j = idx & 63, t = idx >> 6, g = t % 3, k2 = t / 3;
        const float* s = w_hh + (g*64 + j)*64 + 2*k2;
        WPhh2[idx] = h2rn(s[0], s[1]);
    } else if (idx < 12288) {                // WR2p: retrieved half of w_ih
        int i = idx - 6144;
        int j = i & 63, t = i >> 6, g = t % 3, k2 = t / 3;
        const float* s = w_ih + (g*64 + j)*128 + 64 + 2*k2;
        WR2p[i] = h2rn(s[0], s[1]);
    } else if (idx < 14336) {                // QP2[k2*64+j]
        int i = idx - 12288;
        int j = i & 63, k2 = i >> 6;
        const float* s = qw + j*64 + 2*k2;
        QP2[i] = h2rn(s[0], s[1]);
    } else if (idx < 15360) {
        int i = idx - 14336;
        int j = i & 63, k4 = i >> 6;
        const float* s = kw + j*64 + 4*k4;
        KWP[i] = make_float4(s[0], s[1], s[2], s[3]);
    } else if (idx < 16384) {
        int i = idx - 15360;
        int j = i & 63, k4 = i >> 6;
        const float* s = vw + j*64 + 4*k4;
        VWP[i] = make_float4(s[0], s[1], s[2], s[3]);
    }
}

// ---------------- G[v][o] = sum_k embed[v][k]*w_ih[o][k] + b_ih[o] ----------
__global__ __launch_bounds__(64) void build_G(const float* __restrict__ embed_w,
                                              const float* __restrict__ w_ih,
                                              const float* __restrict__ b_ih,
                                              float* __restrict__ G)
{
    int v = blockIdx.x, j = threadIdx.x;
    __shared__ float e_s[64];
    e_s[j] = embed_w[v*64 + j];
    __syncthreads();
    float a0 = b_ih[j], a1 = b_ih[64 + j], a2 = b_ih[128 + j];
    for (int k = 0; k < 64; ++k) {
        float e = e_s[k];
        a0 += e * w_ih[j*128 + k];
        a1 += e * w_ih[(64 + j)*128 + k];
        a2 += e * w_ih[(128 + j)*128 + k];
    }
    G[v*192 + j]       = a0;
    G[v*192 + 64 + j]  = a1;
    G[v*192 + 128 + j] = a2;
}

// ---------------- k/v precompute (kT hh-pair-interleaved u32; v fp16) --------
__global__ __launch_bounds__(256) void compute_kv(const float* __restrict__ memory,
                                                  const float* __restrict__ key_b,
                                                  const float* __restrict__ val_b,
                                                  const float4* __restrict__ KWP,
                                                  const float4* __restrict__ VWP,
                                                  unsigned* __restrict__ kT2,
                                                  __half* __restrict__ v_h)
{
    int wid = threadIdx.x >> 6;
    int o   = threadIdx.x & 63;
    int row = blockIdx.x * 4 + wid;          // row = b*256 + m
    int b = row >> 8, m = row & 255;
    __shared__ __align__(16) float mem_s[4][64];
    mem_s[wid][o] = memory[(size_t)row * 64 + o];
    __syncthreads();
    float ak = key_b[o], av = val_b[o];
    const float4* m4 = (const float4*)mem_s[wid];
#pragma unroll
    for (int k4 = 0; k4 < 16; ++k4) {
        float4 mm = m4[k4];
        ak += dot4(mm, KWP[k4*64 + o]);
        av += dot4(mm, VWP[k4*64 + o]);
    }
    float nb = __shfl_xor(ak, 1);            // k[o^1][m]
    if ((o & 1) == 0)                        // pair (k[o][m], k[o+1][m])
        kT2[((size_t)b*32 + (o >> 1))*256 + m] = h2rn(ak, nb);
    v_h[(size_t)row*64 + o] = __float2half(av);
}

// one GRU step: h broadcast as half2 via readlane; dot2 matvec; no LDS
#define GRU_STEP(cg0, cg1, cg2) do {                                        \
    float gr = (cg0) + RrB, gz = (cg1) + RzB, gn = bhn;                     \
    _Pragma("unroll")                                                       \
    for (int kp = 0; kp < 32; ++kp) {                                       \
        h2v hhp = bch(rl_u(hpu, 2*kp));                                     \
        gr = FDOT2(hhp, wr2[kp], gr);                                       \
        gz = FDOT2(hhp, wz2[kp], gz);                                       \
        gn = FDOT2(hhp, wn2[kp], gn);                                       \
    }                                                                       \
    float r_ = sigm(gr);                                                    \
    float z_ = sigm(gz);                                                    \
    float n_ = tanh_f(((cg2) + Rn) + r_ * gn);                              \
    h = fmaf(z_, h - n_, n_);                                               \
    float hx_ = __shfl_xor(h, 1);                                           \
    hpu = packpair(h, hx_, odd);                                            \
} while (0)

// ---------------- main recurrent kernel: 1 wave per batch element ------------
__global__ __launch_bounds__(64, 1) void recurrent_main(
    const int*   __restrict__ seq,
    const float* __restrict__ b_hh,
    const float* __restrict__ query_b,
    const float* __restrict__ head_w,
    const float* __restrict__ head_b,
    const unsigned* __restrict__ kT2g,
    const __half* __restrict__ v_h,
    const float* __restrict__ G,
    const unsigned* __restrict__ WPhh2,
    const unsigned* __restrict__ WR2p,
    const unsigned* __restrict__ QP2g,
    float* __restrict__ out)
{
    const int b = blockIdx.x;
    const int j = threadIdx.x;
    const bool odd = (j & 1);

    extern __shared__ __align__(16) char smem[];
    const uint4* kT2_lds = (const uint4*)(smem + S_KT);  // [hh2*64 + j]: 4 m-pairs
    const uint2* v_u2    = (const uint2*)(smem + S_V);   // [m*16 + o4]
    const unsigned* qp2  = (const unsigned*)(smem + S_QP); // [k2*64 + j]
    float4* p_s4  = (float4*)(smem + S_P);

    // ---- stage kT2, v, QP2 into LDS once ----
    {
        const uint4* kTg = (const uint4*)(kT2g + (size_t)b * 8192);
        const uint4* vg  = (const uint4*)(v_h  + (size_t)b * 16384);
        uint4* kTls = (uint4*)(smem + S_KT);
        uint4* vls  = (uint4*)(smem + S_V);
#pragma unroll
        for (int i = 0; i < 32; ++i) {
            kTls[i*64 + j] = kTg[i*64 + j];
            vls[i*64 + j]  = vg[i*64 + j];
        }
        const uint4* qpg = (const uint4*)QP2g;
        uint4* qls = (uint4*)(smem + S_QP);
#pragma unroll
        for (int i = 0; i < 8; ++i) qls[i*64 + j] = qpg[i*64 + j];
    }

    // ---- W_hh in registers as half2: 96 words (compiler parks in AGPRs) ----
    h2v wr2[32], wz2[32], wn2[32];
#pragma unroll
    for (int k2 = 0; k2 < 32; ++k2) {
        wr2[k2] = bch(WPhh2[(k2*3 + 0)*64 + j]);
        wz2[k2] = bch(WPhh2[(k2*3 + 1)*64 + j]);
        wn2[k2] = bch(WPhh2[(k2*3 + 2)*64 + j]);
    }

    float h = 0.f;                       // lane j owns h[j]; never leaves regs
    unsigned hpu = 0u;                   // packed (h[2t], h[2t+1]) fp16 pair
    const float bhr = b_hh[j], bhz = b_hh[64 + j], bhn = b_hh[128 + j];
    const float qb  = query_b[j];

    const int* seqb = seq + (size_t)b * L_;
    const int4* sp4 = (const int4*)seqb;
    const int o4 = j & 15;        // h-quad owned in v-loop
    const int mg = j >> 4;        // m-group 0..3
    __builtin_amdgcn_wave_barrier();

    // ---- pipeline prologue: chunk-0 tokens + group-0 G rows ----
    int4 t1 = sp4[1], t2 = sp4[2], t3 = sp4[3];
    float nA0, nA1, nA2, nB0, nB1, nB2, nC0, nC1, nC2, nD0, nD1, nD2;
    {
        int4 t0 = sp4[0];
        const float* PA = G + t0.x*192;
        const float* PB = G + t0.y*192;
        const float* PC = G + t0.z*192;
        const float* PD = G + t0.w*192;
        nA0 = PA[j]; nA1 = PA[64+j]; nA2 = PA[128+j];
        nB0 = PB[j]; nB1 = PB[64+j]; nB2 = PB[128+j];
        nC0 = PC[j]; nC1 = PC[64+j]; nC2 = PC[128+j];
        nD0 = PD[j]; nD1 = PD[64+j]; nD2 = PD[128+j];
    }

    for (int c = 0; c < C_; ++c) {
        // ---- q[j] = qb + sum_k h[k]*Wq[j][k]  (dot2: h pairs + QP2 LDS) ----
        float q = qb;
#pragma unroll 8
        for (int k2 = 0; k2 < 32; ++k2) {
            h2v pp = bch(qp2[k2*64 + j]);
            h2v hh = bch(rl_u(hpu, 2*k2));
            q = FDOT2(hh, pp, q);
        }

        // ---- scores: lane j owns m = 4j..4j+3 (dot2 over hh-pairs) ----
        float qx = __shfl_xor(q, 1);
        unsigned qpu = packpair(q, qx, odd);
        float s0 = 0.f, s1 = 0.f, s2 = 0.f, s3 = 0.f;
#pragma unroll 8
        for (int t = 0; t < 32; ++t) {
            h2v qq = bch(rl_u(qpu, 2*t));
            uint4 kk = kT2_lds[t*64 + j];
            s0 = FDOT2(bch(kk.x), qq, s0);
            s1 = FDOT2(bch(kk.y), qq, s1);
            s2 = FDOT2(bch(kk.z), qq, s2);
            s3 = FDOT2(bch(kk.w), qq, s3);
        }
        const float scale = 0.125f;
        // softmax, no max-sub (|s| small), rcp not div
        float4 p;
        p.x = __expf(s0*scale); p.y = __expf(s1*scale);
        p.z = __expf(s2*scale); p.w = __expf(s3*scale);
        // write p to LDS FIRST, then reduce: the 6-shfl sum chain can then
        // interleave with the v-loop's LDS reads (inv only needed at end).
        p_s4[j] = p;
        __builtin_amdgcn_wave_barrier();
        float sum = (p.x + p.y) + (p.z + p.w);
#pragma unroll
        for (int o = 32; o > 0; o >>= 1) sum += __shfl_xor(sum, o);
        float inv = fast_rcp(sum);

        // ---- retrieved: lane (mg,o4) over m = 4i+mg (fp16 v, pk fp32) ----
        const float* ps = (const float*)p_s4;
        v2f aA0 = {0.f,0.f}, aB0 = {0.f,0.f};
        v2f aA1 = {0.f,0.f}, aB1 = {0.f,0.f};
#pragma unroll 4
        for (int i = 0; i < 64; i += 2) {
            int m0 = 4*i + mg, m1 = 4*(i + 1) + mg;
            float p0 = ps[m0], p1 = ps[m1];
            v2f v0l, v0h, v1l, v1h;
            cvt2v(v_u2[m0*16 + o4], v0l, v0h);
            cvt2v(v_u2[m1*16 + o4], v1l, v1h);
            aA0 += v0l * p0; aB0 += v0h * p0;
            aA1 += v1l * p1; aB1 += v1h * p1;
        }
        float4 acc;
        acc.x = (aA0[0] + aA1[0]) * inv;
        acc.y = (aA0[1] + aA1[1]) * inv;
        acc.z = (aB0[0] + aB1[0]) * inv;
        acc.w = (aB0[1] + aB1[1]) * inv;
#pragma unroll
        for (int o = 16; o <= 32; o <<= 1) {
            acc.x += __shfl_xor(acc.x, o);
            acc.y += __shfl_xor(acc.y, o);
            acc.z += __shfl_xor(acc.z, o);
            acc.w += __shfl_xor(acc.w, o);
        }
        // lane t (and t+16/32/48) holds ret[4t..4t+3] in acc

        // ---- R matvec: ret packed fp16 pairs + WR2p global (dot2) ----
        unsigned rp0 = packpair(acc.x, acc.y, false);  // (ret[4t], ret[4t+1])
        unsigned rp1 = packpair(acc.z, acc.w, false);  // (ret[4t+2], ret[4t+3])
        float Rr = 0.f, Rz = 0.f, Rn = 0.f;
#pragma unroll 8
        for (int k2 = 0; k2 < 32; ++k2) {
            unsigned rsel = (k2 & 1) ? rp1 : rp0;
            h2v rr = bch(rl_u(rsel, k2 >> 1));
            Rr = FDOT2(rr, bch(WR2p[(k2*3 + 0)*64 + j]), Rr);
            Rz = FDOT2(rr, bch(WR2p[(k2*3 + 1)*64 + j]), Rz);
            Rn = FDOT2(rr, bch(WR2p[(k2*3 + 2)*64 + j]), Rn);
        }
        const float RrB = Rr + bhr, RzB = Rz + bhz;

        // ---- token queue: load chunk c+1's tokens (independent, issues
        //      early); queue = [t1, t2, t3, next-t0] for group prefetch ----
        int off = (c + 1 < C_) ? (c + 1) * 4 : 0;   // int4 units
        int4 u0 = sp4[off + 0], u1 = sp4[off + 1];
        int4 u2 = sp4[off + 2], u3 = sp4[off + 3];
        int4 r1 = t1, r2 = t2, r3 = t3, r4 = u0;
        t1 = u1; t2 = u2; t3 = u3;

        // ---- 16 GRU steps: 4 dynamic groups x 4 unrolled.  Group g's steps
        //      hide group g+1's G loads; g=3 prefetches next chunk's group 0
        //      (also hidden under the whole next attention phase). ----
#pragma unroll 1
        for (int g = 0; g < 4; ++g) {
            float cA0=nA0, cA1=nA1, cA2=nA2;
            float cB0=nB0, cB1=nB1, cB2=nB2;
            float cC0=nC0, cC1=nC1, cC2=nC2;
            float cD0=nD0, cD1=nD1, cD2=nD2;
            const float* PA = G + r1.x*192;
            const float* PB = G + r1.y*192;
            const float* PC = G + r1.z*192;
            const float* PD = G + r1.w*192;
            r1 = r2; r2 = r3; r3 = r4;
            nA0 = PA[j]; nA1 = PA[64+j]; nA2 = PA[128+j];
            nB0 = PB[j]; nB1 = PB[64+j]; nB2 = PB[128+j];
            nC0 = PC[j]; nC1 = PC[64+j]; nC2 = PC[128+j];
            nD0 = PD[j]; nD1 = PD[64+j]; nD2 = PD[128+j];

            GRU_STEP(cA0, cA1, cA2);
            GRU_STEP(cB0, cB1, cB2);
            GRU_STEP(cC0, cC1, cC2);
            GRU_STEP(cD0, cD1, cD2);
        }
    }

    // ---- head: out[b][j] = head_b[j] + sum_k h[k]*head_w[j][k] (fp32) ----
    float o = head_b[j];
#pragma unroll
    for (int k4 = 0; k4 < 16; ++k4) {
        float h0 = rl(h, 4*k4+0), h1 = rl(h, 4*k4+1);
        float h2 = rl(h, 4*k4+2), h3 = rl(h, 4*k4+3);
        const float* hw = head_w + j*64 + 4*k4;
        o += h0*hw[0] + h1*hw[1] + h2*hw[2] + h3*hw[3];
    }
    out[(size_t)b*64 + j] = o;
}

extern "C" void kernel_launch(void* const* d_in, const int* in_sizes, int n_in,
                              void* d_out, int out_size, void* d_ws, size_t ws_size,
                              hipStream_t stream) {
    const int*   seq      = (const int*)  d_in[0];
    const float* memory   = (const float*)d_in[1];
    const float* embed_w  = (const float*)d_in[2];
    const float* w_ih     = (const float*)d_in[3];
    const float* w_hh     = (const float*)d_in[4];
    const float* b_ih     = (const float*)d_in[5];
    const float* b_hh     = (const float*)d_in[6];
    const float* key_w    = (const float*)d_in[7];
    const float* key_b    = (const float*)d_in[8];
    const float* val_w    = (const float*)d_in[9];
    const float* val_b    = (const float*)d_in[10];
    const float* query_w  = (const float*)d_in[11];
    const float* query_b  = (const float*)d_in[12];
    const float* head_w   = (const float*)d_in[13];
    const float* head_b   = (const float*)d_in[14];

    char* ws = (char*)d_ws;
    unsigned* kT2  = (unsigned*)(ws + WS_KT);
    __half*   v_h  = (__half*)  (ws + WS_V);
    float*    G    = (float*)   (ws + WS_G);
    unsigned* WPhh2 = (unsigned*)(ws + WS_WPHH);
    unsigned* WR2p  = (unsigned*)(ws + WS_WR);
    unsigned* QP2   = (unsigned*)(ws + WS_QP);
    float4*   KWP   = (float4*)  (ws + WS_KWP);
    float4*   VWP   = (float4*)  (ws + WS_VWP);

    (void)hipFuncSetAttribute((const void*)recurrent_main,
                              hipFuncAttributeMaxDynamicSharedMemorySize,
                              (int)SMEM_BYTES);

    pack_weights<<<64, 256, 0, stream>>>(w_ih, w_hh, query_w, key_w, val_w,
                                         WPhh2, WR2p, QP2, KWP, VWP);
    build_G<<<64, 64, 0, stream>>>(embed_w, w_ih, b_ih, G);
    compute_kv<<<(B_*M_)/4, 256, 0, stream>>>(memory, key_b, val_b, KWP, VWP, kT2, v_h);
    recurrent_main<<<B_, 64, SMEM_BYTES, stream>>>(seq, b_hh, query_b, head_w, head_b,
                                                   kT2, v_h, G, WPhh2, WR2p, QP2,
                                                   (float*)d_out);
}

// Round 4
// 1502.435 us; speedup vs baseline: 1.2044x; 1.1686x over previous
//
#include <hip/hip_runtime.h>
#include <hip/hip_fp16.h>

// FixedFreqModel: B=512, L=2048, M=256, H=64, VOCAB=64, READ_FREQ=16.
// R16 = R12 (best measured, 1380us) + exactly ONE change:
//   WR2p (retrieved-half of w_ih, 96 half2 words) loaded ONCE into register
//   arrays rr2/rz2/rn2 exactly like wr2/wz2/wn2 (no asm pins, no waves_per_eu
//   -- R13 showed pins cause accvgpr churn; unpinned arrays park in AGPRs
//   for free), and the R matvec loop FULLY unrolled so every register index
//   is compile-time (R13 used unroll-8 over a register array = dynamic index
//   hazard). This removes 96 global L2 loads per chunk (12288 per wave) from
//   the serial chain.
// Everything else is byte-identical to R12: original softmax order, original
// G-load placement inside the group loop, no prefetch queues (R14's rotation
// pipeline regressed 13% from register-pressure/copy overhead).

#define B_ 512
#define L_ 2048
#define M_ 256
#define H_ 64
#define C_ 128
#define F_ 16

typedef float v2f __attribute__((ext_vector_type(2)));
typedef _Float16 h2v __attribute__((ext_vector_type(2)));

#if __has_builtin(__builtin_amdgcn_fdot2)
__device__ __forceinline__ float FDOT2(h2v a, h2v b, float c) {
    return __builtin_amdgcn_fdot2(a, b, c, false);
}
#else
__device__ __forceinline__ float FDOT2(h2v a, h2v b, float c) {
    return c + (float)a[0]*(float)b[0] + (float)a[1]*(float)b[1];
}
#endif

__device__ __forceinline__ h2v bch(unsigned u) { return __builtin_bit_cast(h2v, u); }
__device__ __forceinline__ unsigned rl_u(unsigned v, int lane) {
    return (unsigned)__builtin_amdgcn_readlane((int)v, lane);
}
__device__ __forceinline__ float rl(float v, int lane) {
    return __int_as_float(__builtin_amdgcn_readlane(__float_as_int(v), lane));
}
// pack (mine, neighbor) -> half2 in lane order (even idx first)
__device__ __forceinline__ unsigned packpair(float mine, float other, bool odd) {
    float lo = odd ? other : mine;
    float hi = odd ? mine : other;
    auto r = __builtin_amdgcn_cvt_pkrtz(lo, hi);   // __fp16 ext_vector(2)
    return __builtin_bit_cast(unsigned, r);
}
__device__ __forceinline__ float dot4(float4 a, float4 b) {
    return a.x*b.x + a.y*b.y + a.z*b.z + a.w*b.w;
}
__device__ __forceinline__ void cvt2v(uint2 raw, v2f& lo, v2f& hi) {
    __half2* hp = (__half2*)&raw;
    float2 a = __half22float2(hp[0]);
    float2 b = __half22float2(hp[1]);
    lo[0] = a.x; lo[1] = a.y; hi[0] = b.x; hi[1] = b.y;
}
__device__ __forceinline__ float fast_rcp(float x) { return __builtin_amdgcn_rcpf(x); }
__device__ __forceinline__ float sigm(float x) { return fast_rcp(1.f + __expf(-x)); }
__device__ __forceinline__ float tanh_f(float x) {
    float e2 = __expf(-2.f * fabsf(x));
    return copysignf((1.f - e2) * fast_rcp(1.f + e2), x);
}
__device__ __forceinline__ unsigned h2rn(float a, float b) {
    __half2 h = __floats2half2_rn(a, b);
    return __builtin_bit_cast(unsigned, h);
}

// workspace offsets (bytes)
#define WS_KT    0u            // kT2: 512 * 8192 u32 = 16 MB  [b][hh2][m]
#define WS_V     16777216u     // v fp16: 16 MB [b][m][o]
#define WS_G     33554432u     // 64*192 fp32 = 48 KB
#define WS_WPHH  33603584u     // 6144 u32 = 24 KB  [(k2*3+g)*64+j]
#define WS_WR    33628160u     // 6144 u32 = 24 KB
#define WS_QP    33652736u     // 2048 u32 = 8 KB   [k2*64+j]
#define WS_KWP   33660928u     // 1024 float4 = 16 KB
#define WS_VWP   33677312u     // 16 KB

// dynamic LDS layout (bytes)
#define S_KT   0u        // 32768 : kT2 u32 [hh2=32][m=256]  (uint4 per (hh2, 4m))
#define S_V    32768u    // 32768 : v half [m][o]
#define S_QP   65536u    // 8192  : QP2 u32 [k2=32][j=64]
#define S_P    73728u    // 1024  : float4 p_s[64]
#define SMEM_BYTES 74752u

// ---------------- pack weights -----------------------------------------------
__global__ void pack_weights(const float* __restrict__ w_ih,
                             const float* __restrict__ w_hh,
                             const float* __restrict__ qw,
                             const float* __restrict__ kw,
                             const float* __restrict__ vw,
                             unsigned* __restrict__ WPhh2,
                             unsigned* __restrict__ WR2p,
                             unsigned* __restrict__ QP2,
                             float4* __restrict__ KWP,
                             float4* __restrict__ VWP)
{
    int idx = blockIdx.x * 256 + threadIdx.x;
    if (idx < 6144) {                        // WPhh2[(k2*3+g)*64+j]
        int j = idx & 63, t = idx >> 6, g = t % 3, k2 = t / 3;
        const float* s = w_hh + (g*64 + j)*64 + 2*k2;
        WPhh2[idx] = h2rn(s[0], s[1]);
    } else if (idx < 12288) {                // WR2p: retrieved half of w_ih
        int i = idx - 6144;
        int j = i & 63, t = i >> 6, g = t % 3, k2 = t / 3;
        const float* s = w_ih + (g*64 + j)*128 + 64 + 2*k2;
        WR2p[i] = h2rn(s[0], s[1]);
    } else if (idx < 14336) {                // QP2[k2*64+j]
        int i = idx - 12288;
        int j = i & 63, k2 = i >> 6;
        const float* s = qw + j*64 + 2*k2;
        QP2[i] = h2rn(s[0], s[1]);
    } else if (idx < 15360) {
        int i = idx - 14336;
        int j = i & 63, k4 = i >> 6;
        const float* s = kw + j*64 + 4*k4;
        KWP[i] = make_float4(s[0], s[1], s[2], s[3]);
    } else if (idx < 16384) {
        int i = idx - 15360;
        int j = i & 63, k4 = i >> 6;
        const float* s = vw + j*64 + 4*k4;
        VWP[i] = make_float4(s[0], s[1], s[2], s[3]);
    }
}

// ---------------- G[v][o] = sum_k embed[v][k]*w_ih[o][k] + b_ih[o] ----------
__global__ __launch_bounds__(64) void build_G(const float* __restrict__ embed_w,
                                              const float* __restrict__ w_ih,
                                              const float* __restrict__ b_ih,
                                              float* __restrict__ G)
{
    int v = blockIdx.x, j = threadIdx.x;
    __shared__ float e_s[64];
    e_s[j] = embed_w[v*64 + j];
    __syncthreads();
    float a0 = b_ih[j], a1 = b_ih[64 + j], a2 = b_ih[128 + j];
    for (int k = 0; k < 64; ++k) {
        float e = e_s[k];
        a0 += e * w_ih[j*128 + k];
        a1 += e * w_ih[(64 + j)*128 + k];
        a2 += e * w_ih[(128 + j)*128 + k];
    }
    G[v*192 + j]       = a0;
    G[v*192 + 64 + j]  = a1;
    G[v*192 + 128 + j] = a2;
}

// ---------------- k/v precompute (kT hh-pair-interleaved u32; v fp16) --------
__global__ __launch_bounds__(256) void compute_kv(const float* __restrict__ memory,
                                                  const float* __restrict__ key_b,
                                                  const float* __restrict__ val_b,
                                                  const float4* __restrict__ KWP,
                                                  const float4* __restrict__ VWP,
                                                  unsigned* __restrict__ kT2,
                                                  __half* __restrict__ v_h)
{
    int wid = threadIdx.x >> 6;
    int o   = threadIdx.x & 63;
    int row = blockIdx.x * 4 + wid;          // row = b*256 + m
    int b = row >> 8, m = row & 255;
    __shared__ __align__(16) float mem_s[4][64];
    mem_s[wid][o] = memory[(size_t)row * 64 + o];
    __syncthreads();
    float ak = key_b[o], av = val_b[o];
    const float4* m4 = (const float4*)mem_s[wid];
#pragma unroll
    for (int k4 = 0; k4 < 16; ++k4) {
        float4 mm = m4[k4];
        ak += dot4(mm, KWP[k4*64 + o]);
        av += dot4(mm, VWP[k4*64 + o]);
    }
    float nb = __shfl_xor(ak, 1);            // k[o^1][m]
    if ((o & 1) == 0)                        // pair (k[o][m], k[o+1][m])
        kT2[((size_t)b*32 + (o >> 1))*256 + m] = h2rn(ak, nb);
    v_h[(size_t)row*64 + o] = __float2half(av);
}

// one GRU step: h broadcast as half2 via readlane; dot2 matvec; no LDS
#define GRU_STEP(cg0, cg1, cg2) do {                                        \
    float gr = (cg0) + RrB, gz = (cg1) + RzB, gn = bhn;                     \
    _Pragma("unroll")                                                       \
    for (int kp = 0; kp < 32; ++kp) {                                       \
        h2v hhp = bch(rl_u(hpu, 2*kp));                                     \
        gr = FDOT2(hhp, wr2[kp], gr);                                       \
        gz = FDOT2(hhp, wz2[kp], gz);                                       \
        gn = FDOT2(hhp, wn2[kp], gn);                                       \
    }                                                                       \
    float r_ = sigm(gr);                                                    \
    float z_ = sigm(gz);                                                    \
    float n_ = tanh_f(((cg2) + Rn) + r_ * gn);                              \
    h = fmaf(z_, h - n_, n_);                                               \
    float hx_ = __shfl_xor(h, 1);                                           \
    hpu = packpair(h, hx_, odd);                                            \
} while (0)

// ---------------- main recurrent kernel: 1 wave per batch element ------------
__global__ __launch_bounds__(64, 1) void recurrent_main(
    const int*   __restrict__ seq,
    const float* __restrict__ b_hh,
    const float* __restrict__ query_b,
    const float* __restrict__ head_w,
    const float* __restrict__ head_b,
    const unsigned* __restrict__ kT2g,
    const __half* __restrict__ v_h,
    const float* __restrict__ G,
    const unsigned* __restrict__ WPhh2,
    const unsigned* __restrict__ WR2p,
    const unsigned* __restrict__ QP2g,
    float* __restrict__ out)
{
    const int b = blockIdx.x;
    const int j = threadIdx.x;
    const bool odd = (j & 1);

    extern __shared__ __align__(16) char smem[];
    const uint4* kT2_lds = (const uint4*)(smem + S_KT);  // [hh2*64 + j]: 4 m-pairs
    const uint2* v_u2    = (const uint2*)(smem + S_V);   // [m*16 + o4]
    const unsigned* qp2  = (const unsigned*)(smem + S_QP); // [k2*64 + j]
    float4* p_s4  = (float4*)(smem + S_P);

    // ---- stage kT2, v, QP2 into LDS once ----
    {
        const uint4* kTg = (const uint4*)(kT2g + (size_t)b * 8192);
        const uint4* vg  = (const uint4*)(v_h  + (size_t)b * 16384);
        uint4* kTls = (uint4*)(smem + S_KT);
        uint4* vls  = (uint4*)(smem + S_V);
#pragma unroll
        for (int i = 0; i < 32; ++i) {
            kTls[i*64 + j] = kTg[i*64 + j];
            vls[i*64 + j]  = vg[i*64 + j];
        }
        const uint4* qpg = (const uint4*)QP2g;
        uint4* qls = (uint4*)(smem + S_QP);
#pragma unroll
        for (int i = 0; i < 8; ++i) qls[i*64 + j] = qpg[i*64 + j];
    }

    // ---- W_hh in registers as half2: 96 words (compiler parks in AGPRs) ----
    h2v wr2[32], wz2[32], wn2[32];
#pragma unroll
    for (int k2 = 0; k2 < 32; ++k2) {
        wr2[k2] = bch(WPhh2[(k2*3 + 0)*64 + j]);
        wz2[k2] = bch(WPhh2[(k2*3 + 1)*64 + j]);
        wn2[k2] = bch(WPhh2[(k2*3 + 2)*64 + j]);
    }
    // ---- WR (retrieved-half of w_ih) likewise: 96 words, loaded ONCE ----
    h2v rr2[32], rz2[32], rn2[32];
#pragma unroll
    for (int k2 = 0; k2 < 32; ++k2) {
        rr2[k2] = bch(WR2p[(k2*3 + 0)*64 + j]);
        rz2[k2] = bch(WR2p[(k2*3 + 1)*64 + j]);
        rn2[k2] = bch(WR2p[(k2*3 + 2)*64 + j]);
    }

    float h = 0.f;                       // lane j owns h[j]; never leaves regs
    unsigned hpu = 0u;                   // packed (h[2t], h[2t+1]) fp16 pair
    const float bhr = b_hh[j], bhz = b_hh[64 + j], bhn = b_hh[128 + j];
    const float qb  = query_b[j];

    const int* seqb = seq + (size_t)b * L_;
    const int o4 = j & 15;        // h-quad owned in v-loop
    const int mg = j >> 4;        // m-group 0..3
    __builtin_amdgcn_wave_barrier();

    for (int c = 0; c < C_; ++c) {
        const int c16 = c * F_;

        // ---- q[j] = qb + sum_k h[k]*Wq[j][k]  (dot2: h pairs + QP2 LDS) ----
        float q = qb;
#pragma unroll 8
        for (int k2 = 0; k2 < 32; ++k2) {
            h2v pp = bch(qp2[k2*64 + j]);
            h2v hh = bch(rl_u(hpu, 2*k2));
            q = FDOT2(hh, pp, q);
        }

        // ---- scores: lane j owns m = 4j..4j+3 (dot2 over hh-pairs) ----
        float qx = __shfl_xor(q, 1);
        unsigned qpu = packpair(q, qx, odd);
        float s0 = 0.f, s1 = 0.f, s2 = 0.f, s3 = 0.f;
#pragma unroll 8
        for (int t = 0; t < 32; ++t) {
            h2v qq = bch(rl_u(qpu, 2*t));
            uint4 kk = kT2_lds[t*64 + j];
            s0 = FDOT2(bch(kk.x), qq, s0);
            s1 = FDOT2(bch(kk.y), qq, s1);
            s2 = FDOT2(bch(kk.z), qq, s2);
            s3 = FDOT2(bch(kk.w), qq, s3);
        }
        const float scale = 0.125f;
        // softmax, no max-sub (|s| small), rcp not div
        float4 p;
        p.x = __expf(s0*scale); p.y = __expf(s1*scale);
        p.z = __expf(s2*scale); p.w = __expf(s3*scale);
        float sum = (p.x + p.y) + (p.z + p.w);
#pragma unroll
        for (int o = 32; o > 0; o >>= 1) sum += __shfl_xor(sum, o);
        float inv = fast_rcp(sum);
        p_s4[j] = p;
        __builtin_amdgcn_wave_barrier();

        // ---- retrieved: lane (mg,o4) over m = 4i+mg (fp16 v, pk fp32) ----
        const float* ps = (const float*)p_s4;
        v2f aA0 = {0.f,0.f}, aB0 = {0.f,0.f};
        v2f aA1 = {0.f,0.f}, aB1 = {0.f,0.f};
#pragma unroll 4
        for (int i = 0; i < 64; i += 2) {
            int m0 = 4*i + mg, m1 = 4*(i + 1) + mg;
            float p0 = ps[m0], p1 = ps[m1];
            v2f v0l, v0h, v1l, v1h;
            cvt2v(v_u2[m0*16 + o4], v0l, v0h);
            cvt2v(v_u2[m1*16 + o4], v1l, v1h);
            aA0 += v0l * p0; aB0 += v0h * p0;
            aA1 += v1l * p1; aB1 += v1h * p1;
        }
        float4 acc;
        acc.x = (aA0[0] + aA1[0]) * inv;
        acc.y = (aA0[1] + aA1[1]) * inv;
        acc.z = (aB0[0] + aB1[0]) * inv;
        acc.w = (aB0[1] + aB1[1]) * inv;
#pragma unroll
        for (int o = 16; o <= 32; o <<= 1) {
            acc.x += __shfl_xor(acc.x, o);
            acc.y += __shfl_xor(acc.y, o);
            acc.z += __shfl_xor(acc.z, o);
            acc.w += __shfl_xor(acc.w, o);
        }
        // lane t (and t+16/32/48) holds ret[4t..4t+3] in acc

        // ---- R matvec: ret packed fp16 pairs + WR words in regs (dot2).
        //      FULL unroll: every rr2/rz2/rn2 index is compile-time. ----
        unsigned rp0 = packpair(acc.x, acc.y, false);  // (ret[4t], ret[4t+1])
        unsigned rp1 = packpair(acc.z, acc.w, false);  // (ret[4t+2], ret[4t+3])
        float Rr = 0.f, Rz = 0.f, Rn = 0.f;
#pragma unroll
        for (int k2 = 0; k2 < 32; ++k2) {
            unsigned rsel = (k2 & 1) ? rp1 : rp0;
            h2v rr = bch(rl_u(rsel, k2 >> 1));
            Rr = FDOT2(rr, rr2[k2], Rr);
            Rz = FDOT2(rr, rz2[k2], Rz);
            Rn = FDOT2(rr, rn2[k2], Rn);
        }
        const float RrB = Rr + bhr, RzB = Rz + bhz;

        // ---- 16 GRU steps: 4 dynamic groups x 4 unrolled (I-cache OK).
        //      Tokens: one uniform int4 load/group; 12 named G regs. ----
#pragma unroll 1
        for (int g = 0; g < 4; ++g) {
            const int4 tg = *(const int4*)(seqb + c16 + 4*g);
            const float* GA = G + tg.x*192;
            const float* GB = G + tg.y*192;
            const float* GC = G + tg.z*192;
            const float* GD = G + tg.w*192;
            float gA0 = GA[j], gA1 = GA[64+j], gA2 = GA[128+j];
            float gB0 = GB[j], gB1 = GB[64+j], gB2 = GB[128+j];
            float gC0 = GC[j], gC1 = GC[64+j], gC2 = GC[128+j];
            float gD0 = GD[j], gD1 = GD[64+j], gD2 = GD[128+j];

            GRU_STEP(gA0, gA1, gA2);
            GRU_STEP(gB0, gB1, gB2);
            GRU_STEP(gC0, gC1, gC2);
            GRU_STEP(gD0, gD1, gD2);
        }
    }

    // ---- head: out[b][j] = head_b[j] + sum_k h[k]*head_w[j][k] (fp32) ----
    float o = head_b[j];
#pragma unroll
    for (int k4 = 0; k4 < 16; ++k4) {
        float h0 = rl(h, 4*k4+0), h1 = rl(h, 4*k4+1);
        float h2 = rl(h, 4*k4+2), h3 = rl(h, 4*k4+3);
        const float* hw = head_w + j*64 + 4*k4;
        o += h0*hw[0] + h1*hw[1] + h2*hw[2] + h3*hw[3];
    }
    out[(size_t)b*64 + j] = o;
}

extern "C" void kernel_launch(void* const* d_in, const int* in_sizes, int n_in,
                              void* d_out, int out_size, void* d_ws, size_t ws_size,
                              hipStream_t stream) {
    const int*   seq      = (const int*)  d_in[0];
    const float* memory   = (const float*)d_in[1];
    const float* embed_w  = (const float*)d_in[2];
    const float* w_ih     = (const float*)d_in[3];
    const float* w_hh     = (const float*)d_in[4];
    const float* b_ih     = (const float*)d_in[5];
    const float* b_hh     = (const float*)d_in[6];
    const float* key_w    = (const float*)d_in[7];
    const float* key_b    = (const float*)d_in[8];
    const float* val_w    = (const float*)d_in[9];
    const float* val_b    = (const float*)d_in[10];
    const float* query_w  = (const float*)d_in[11];
    const float* query_b  = (const float*)d_in[12];
    const float* head_w   = (const float*)d_in[13];
    const float* head_b   = (const float*)d_in[14];

    char* ws = (char*)d_ws;
    unsigned* kT2  = (unsigned*)(ws + WS_KT);
    __half*   v_h  = (__half*)  (ws + WS_V);
    float*    G    = (float*)   (ws + WS_G);
    unsigned* WPhh2 = (unsigned*)(ws + WS_WPHH);
    unsigned* WR2p  = (unsigned*)(ws + WS_WR);
    unsigned* QP2   = (unsigned*)(ws + WS_QP);
    float4*   KWP   = (float4*)  (ws + WS_KWP);
    float4*   VWP   = (float4*)  (ws + WS_VWP);

    (void)hipFuncSetAttribute((const void*)recurrent_main,
                              hipFuncAttributeMaxDynamicSharedMemorySize,
                              (int)SMEM_BYTES);

    pack_weights<<<64, 256, 0, stream>>>(w_ih, w_hh, query_w, key_w, val_w,
                                         WPhh2, WR2p, QP2, KWP, VWP);
    build_G<<<64, 64, 0, stream>>>(embed_w, w_ih, b_ih, G);
    compute_kv<<<(B_*M_)/4, 256, 0, stream>>>(memory, key_b, val_b, KWP, VWP, kT2, v_h);
    recurrent_main<<<B_, 64, SMEM_BYTES, stream>>>(seq, b_hh, query_b, head_w, head_b,
                                                   kT2, v_h, G, WPhh2, WR2p, QP2,
                                                   (float*)d_out);
}

// Round 5
// 1394.968 us; speedup vs baseline: 1.2972x; 1.0770x over previous
//
#include <hip/hip_runtime.h>
#include <hip/hip_fp16.h>

// FixedFreqModel: B=512, L=2048, M=256, H=64, VOCAB=64, READ_FREQ=16.
// R17 = R16 (1308us steady) + two issue/latency reductions on the same skeleton:
//  1. v-loop -> v_dot2_f32_f16 with m-transposed v:
//     - compute_kv writes vT2[b][o][mp] = fp16 pair (v[2mp][o], v[2mp+1][o])
//       (LDS exchange of the 4 m-rows per block, then packed u32 store).
//     - recurrent stages vT2 into LDS with rows padded 128->132 u32 (keeps
//       16B alignment for ds_read_b128; banks spread evenly 8/bank).
//     - softmax writes p as fp16 pairs (cvt_pkrtz, unnormalized; fp32-exact
//       sum still used for inv, so p-rounding contributes ~1e-5 to ret).
//     - v-loop: lane j owns ret[j]: 32 x (b128 v + b128 broadcast p + 4 dot2)
//       = ~192 insts (was ~640 cvt-heavy insts) and NO cross-lane reduce.
//  2. Token hoist: all 4 token int4s loaded at chunk top (16 VGPRs, no
//     rotation, no cross-chunk live range -- avoids R14's failure mode);
//     group loop selects via cndmask instead of an exposed ~200cy load.
// Weights W_hh + WR stay register-resident (R16). No pins, no waves_per_eu.

#define B_ 512
#define L_ 2048
#define M_ 256
#define H_ 64
#define C_ 128
#define F_ 16

typedef float v2f __attribute__((ext_vector_type(2)));
typedef _Float16 h2v __attribute__((ext_vector_type(2)));

#if __has_builtin(__builtin_amdgcn_fdot2)
__device__ __forceinline__ float FDOT2(h2v a, h2v b, float c) {
    return __builtin_amdgcn_fdot2(a, b, c, false);
}
#else
__device__ __forceinline__ float FDOT2(h2v a, h2v b, float c) {
    return c + (float)a[0]*(float)b[0] + (float)a[1]*(float)b[1];
}
#endif

__device__ __forceinline__ h2v bch(unsigned u) { return __builtin_bit_cast(h2v, u); }
__device__ __forceinline__ unsigned rl_u(unsigned v, int lane) {
    return (unsigned)__builtin_amdgcn_readlane((int)v, lane);
}
__device__ __forceinline__ float rl(float v, int lane) {
    return __int_as_float(__builtin_amdgcn_readlane(__float_as_int(v), lane));
}
// pack (mine, neighbor) -> half2 in lane order (even idx first)
__device__ __forceinline__ unsigned packpair(float mine, float other, bool odd) {
    float lo = odd ? other : mine;
    float hi = odd ? mine : other;
    auto r = __builtin_amdgcn_cvt_pkrtz(lo, hi);   // __fp16 ext_vector(2)
    return __builtin_bit_cast(unsigned, r);
}
__device__ __forceinline__ unsigned pkrtz(float a, float b) {
    auto r = __builtin_amdgcn_cvt_pkrtz(a, b);
    return __builtin_bit_cast(unsigned, r);
}
__device__ __forceinline__ float dot4(float4 a, float4 b) {
    return a.x*b.x + a.y*b.y + a.z*b.z + a.w*b.w;
}
__device__ __forceinline__ float fast_rcp(float x) { return __builtin_amdgcn_rcpf(x); }
__device__ __forceinline__ float sigm(float x) { return fast_rcp(1.f + __expf(-x)); }
__device__ __forceinline__ float tanh_f(float x) {
    float e2 = __expf(-2.f * fabsf(x));
    return copysignf((1.f - e2) * fast_rcp(1.f + e2), x);
}
__device__ __forceinline__ unsigned h2rn(float a, float b) {
    __half2 h = __floats2half2_rn(a, b);
    return __builtin_bit_cast(unsigned, h);
}

// workspace offsets (bytes)
#define WS_KT    0u            // kT2: 512 * 8192 u32 = 16 MB  [b][hh2][m]
#define WS_V     16777216u     // vT2: 512 * 8192 u32 = 16 MB  [b][o][mp]
#define WS_G     33554432u     // 64*192 fp32 = 48 KB
#define WS_WPHH  33603584u     // 6144 u32 = 24 KB  [(k2*3+g)*64+j]
#define WS_WR    33628160u     // 6144 u32 = 24 KB
#define WS_QP    33652736u     // 2048 u32 = 8 KB   [k2*64+j]
#define WS_KWP   33660928u     // 1024 float4 = 16 KB
#define WS_VWP   33677312u     // 16 KB

// dynamic LDS layout (bytes)
#define S_KT   0u        // 32768 : kT2 u32 [hh2=32][m=256]  (uint4 per (hh2, 4m))
#define S_V    32768u    // 33792 : vP u32 [o=64][132] (128 mp-pairs + 4 pad)
#define S_QP   66560u    // 8192  : QP2 u32 [k2=32][j=64]
#define S_P    74752u    // 512   : p fp16 pairs u32 [mp=128]
#define SMEM_BYTES 75264u

// ---------------- pack weights -----------------------------------------------
__global__ void pack_weights(const float* __restrict__ w_ih,
                             const float* __restrict__ w_hh,
                             const float* __restrict__ qw,
                             const float* __restrict__ kw,
                             const float* __restrict__ vw,
                             unsigned* __restrict__ WPhh2,
                             unsigned* __restrict__ WR2p,
                             unsigned* __restrict__ QP2,
                             float4* __restrict__ KWP,
                             float4* __restrict__ VWP)
{
    int idx = blockIdx.x * 256 + threadIdx.x;
    if (idx < 6144) {                        // WPhh2[(k2*3+g)*64+j]
        int j = idx & 63, t = idx >> 6, g = t % 3, k2 = t / 3;
        const float* s = w_hh + (g*64 + j)*64 + 2*k2;
        WPhh2[idx] = h2rn(s[0], s[1]);
    } else if (idx < 12288) {                // WR2p: retrieved half of w_ih
        int i = idx - 6144;
        int j = i & 63, t = i >> 6, g = t % 3, k2 = t / 3;
        const float* s = w_ih + (g*64 + j)*128 + 64 + 2*k2;
        WR2p[i] = h2rn(s[0], s[1]);
    } else if (idx < 14336) {                // QP2[k2*64+j]
        int i = idx - 12288;
        int j = i & 63, k2 = i >> 6;
        const float* s = qw + j*64 + 2*k2;
        QP2[i] = h2rn(s[0], s[1]);
    } else if (idx < 15360) {
        int i = idx - 14336;
        int j = i & 63, k4 = i >> 6;
        const float* s = kw + j*64 + 4*k4;
        KWP[i] = make_float4(s[0], s[1], s[2], s[3]);
    } else if (idx < 16384) {
        int i = idx - 15360;
        int j = i & 63, k4 = i >> 6;
        const float* s = vw + j*64 + 4*k4;
        VWP[i] = make_float4(s[0], s[1], s[2], s[3]);
    }
}

// ---------------- G[v][o] = sum_k embed[v][k]*w_ih[o][k] + b_ih[o] ----------
__global__ __launch_bounds__(64) void build_G(const float* __restrict__ embed_w,
                                              const float* __restrict__ w_ih,
                                              const float* __restrict__ b_ih,
                                              float* __restrict__ G)
{
    int v = blockIdx.x, j = threadIdx.x;
    __shared__ float e_s[64];
    e_s[j] = embed_w[v*64 + j];
    __syncthreads();
    float a0 = b_ih[j], a1 = b_ih[64 + j], a2 = b_ih[128 + j];
    for (int k = 0; k < 64; ++k) {
        float e = e_s[k];
        a0 += e * w_ih[j*128 + k];
        a1 += e * w_ih[(64 + j)*128 + k];
        a2 += e * w_ih[(128 + j)*128 + k];
    }
    G[v*192 + j]       = a0;
    G[v*192 + 64 + j]  = a1;
    G[v*192 + 128 + j] = a2;
}

// ------- k/v precompute (kT hh-pair u32; v m-pair-transposed u32) ------------
__global__ __launch_bounds__(256) void compute_kv(const float* __restrict__ memory,
                                                  const float* __restrict__ key_b,
                                                  const float* __restrict__ val_b,
                                                  const float4* __restrict__ KWP,
                                                  const float4* __restrict__ VWP,
                                                  unsigned* __restrict__ kT2,
                                                  unsigned* __restrict__ vT2)
{
    int wid = threadIdx.x >> 6;
    int o   = threadIdx.x & 63;
    int row = blockIdx.x * 4 + wid;          // row = b*256 + m
    int b = row >> 8, m = row & 255;
    __shared__ __align__(16) float mem_s[4][64];
    __shared__ float avs[4][64];
    mem_s[wid][o] = memory[(size_t)row * 64 + o];
    __syncthreads();
    float ak = key_b[o], av = val_b[o];
    const float4* m4 = (const float4*)mem_s[wid];
#pragma unroll
    for (int k4 = 0; k4 < 16; ++k4) {
        float4 mm = m4[k4];
        ak += dot4(mm, KWP[k4*64 + o]);
        av += dot4(mm, VWP[k4*64 + o]);
    }
    float nb = __shfl_xor(ak, 1);            // k[o^1][m]
    if ((o & 1) == 0)                        // pair (k[o][m], k[o+1][m])
        kT2[((size_t)b*32 + (o >> 1))*256 + m] = h2rn(ak, nb);
    avs[wid][o] = av;
    __syncthreads();
    if ((wid & 1) == 0) {                    // pair (v[m][o], v[m+1][o]), m even
        vT2[((size_t)b*64 + o)*128 + (m >> 1)] = h2rn(avs[wid][o], avs[wid+1][o]);
    }
}

// one GRU step: h broadcast as half2 via readlane; dot2 matvec; no LDS
#define GRU_STEP(cg0, cg1, cg2) do {                                        \
    float gr = (cg0) + RrB, gz = (cg1) + RzB, gn = bhn;                     \
    _Pragma("unroll")                                                       \
    for (int kp = 0; kp < 32; ++kp) {                                       \
        h2v hhp = bch(rl_u(hpu, 2*kp));                                     \
        gr = FDOT2(hhp, wr2[kp], gr);                                       \
        gz = FDOT2(hhp, wz2[kp], gz);                                       \
        gn = FDOT2(hhp, wn2[kp], gn);                                       \
    }                                                                       \
    float r_ = sigm(gr);                                                    \
    float z_ = sigm(gz);                                                    \
    float n_ = tanh_f(((cg2) + Rn) + r_ * gn);                              \
    h = fmaf(z_, h - n_, n_);                                               \
    float hx_ = __shfl_xor(h, 1);                                           \
    hpu = packpair(h, hx_, odd);                                            \
} while (0)

// ---------------- main recurrent kernel: 1 wave per batch element ------------
__global__ __launch_bounds__(64, 1) void recurrent_main(
    const int*   __restrict__ seq,
    const float* __restrict__ b_hh,
    const float* __restrict__ query_b,
    const float* __restrict__ head_w,
    const float* __restrict__ head_b,
    const unsigned* __restrict__ kT2g,
    const unsigned* __restrict__ vT2g,
    const float* __restrict__ G,
    const unsigned* __restrict__ WPhh2,
    const unsigned* __restrict__ WR2p,
    const unsigned* __restrict__ QP2g,
    float* __restrict__ out)
{
    const int b = blockIdx.x;
    const int j = threadIdx.x;
    const bool odd = (j & 1);

    extern __shared__ __align__(16) char smem[];
    const uint4* kT2_lds = (const uint4*)(smem + S_KT);  // [hh2*64 + j]: 4 m-pairs
    const unsigned* qp2  = (const unsigned*)(smem + S_QP); // [k2*64 + j]

    // ---- stage kT2, vT2 (repad 128->132 u32 rows), QP2 into LDS once ----
    {
        const uint4* kTg = (const uint4*)(kT2g + (size_t)b * 8192);
        uint4* kTls = (uint4*)(smem + S_KT);
#pragma unroll
        for (int i = 0; i < 32; ++i) kTls[i*64 + j] = kTg[i*64 + j];
        const uint4* vg4 = (const uint4*)(vT2g + (size_t)b * 8192);
        uint4* vls4 = (uint4*)(smem + S_V);
#pragma unroll
        for (int i = 0; i < 32; ++i) {
            int t = i*64 + j;                 // global quad: o = t>>5, q = t&31
            vls4[(t >> 5)*33 + (t & 31)] = vg4[t];
        }
        const uint4* qpg = (const uint4*)QP2g;
        uint4* qls = (uint4*)(smem + S_QP);
#pragma unroll
        for (int i = 0; i < 8; ++i) qls[i*64 + j] = qpg[i*64 + j];
    }

    // ---- W_hh in registers as half2: 96 words (compiler parks in AGPRs) ----
    h2v wr2[32], wz2[32], wn2[32];
#pragma unroll
    for (int k2 = 0; k2 < 32; ++k2) {
        wr2[k2] = bch(WPhh2[(k2*3 + 0)*64 + j]);
        wz2[k2] = bch(WPhh2[(k2*3 + 1)*64 + j]);
        wn2[k2] = bch(WPhh2[(k2*3 + 2)*64 + j]);
    }
    // ---- WR (retrieved-half of w_ih) likewise: 96 words, loaded ONCE ----
    h2v rr2[32], rz2[32], rn2[32];
#pragma unroll
    for (int k2 = 0; k2 < 32; ++k2) {
        rr2[k2] = bch(WR2p[(k2*3 + 0)*64 + j]);
        rz2[k2] = bch(WR2p[(k2*3 + 1)*64 + j]);
        rn2[k2] = bch(WR2p[(k2*3 + 2)*64 + j]);
    }

    float h = 0.f;                       // lane j owns h[j]; never leaves regs
    unsigned hpu = 0u;                   // packed (h[2t], h[2t+1]) fp16 pair
    const float bhr = b_hh[j], bhz = b_hh[64 + j], bhn = b_hh[128 + j];
    const float qb  = query_b[j];

    const int* seqb = seq + (size_t)b * L_;
    const uint4* vrow = (const uint4*)(smem + S_V) + j*33;   // lane's o-row
    const uint4* p4   = (const uint4*)(smem + S_P);
    __builtin_amdgcn_wave_barrier();

    for (int c = 0; c < C_; ++c) {
        const int c16 = c * F_;

        // ---- token hoist: all 4 group int4s issued at chunk top ----
        const int4 pA = *(const int4*)(seqb + c16);
        const int4 pB = *(const int4*)(seqb + c16 + 4);
        const int4 pC = *(const int4*)(seqb + c16 + 8);
        const int4 pD = *(const int4*)(seqb + c16 + 12);

        // ---- q[j] = qb + sum_k h[k]*Wq[j][k]  (dot2: h pairs + QP2 LDS) ----
        float q = qb;
#pragma unroll 8
        for (int k2 = 0; k2 < 32; ++k2) {
            h2v pp = bch(qp2[k2*64 + j]);
            h2v hh = bch(rl_u(hpu, 2*k2));
            q = FDOT2(hh, pp, q);
        }

        // ---- scores: lane j owns m = 4j..4j+3 (dot2 over hh-pairs) ----
        float qx = __shfl_xor(q, 1);
        unsigned qpu = packpair(q, qx, odd);
        float s0 = 0.f, s1 = 0.f, s2 = 0.f, s3 = 0.f;
#pragma unroll 8
        for (int t = 0; t < 32; ++t) {
            h2v qq = bch(rl_u(qpu, 2*t));
            uint4 kk = kT2_lds[t*64 + j];
            s0 = FDOT2(bch(kk.x), qq, s0);
            s1 = FDOT2(bch(kk.y), qq, s1);
            s2 = FDOT2(bch(kk.z), qq, s2);
            s3 = FDOT2(bch(kk.w), qq, s3);
        }
        const float scale = 0.125f;
        // softmax, no max-sub (|s| small), rcp not div
        float4 p;
        p.x = __expf(s0*scale); p.y = __expf(s1*scale);
        p.z = __expf(s2*scale); p.w = __expf(s3*scale);
        float sum = (p.x + p.y) + (p.z + p.w);
#pragma unroll
        for (int o = 32; o > 0; o >>= 1) sum += __shfl_xor(sum, o);
        float inv = fast_rcp(sum);
        // p as fp16 pairs (unnormalized): mp=2j -> (p[4j],p[4j+1]); 2j+1 -> ...
        *(uint2*)(smem + S_P + (size_t)j*8) =
            make_uint2(pkrtz(p.x, p.y), pkrtz(p.z, p.w));
        __builtin_amdgcn_wave_barrier();

        // ---- retrieved: lane j owns ret[j]; 32 x (v b128 + p b128 + 4 dot2) ----
        float racc = 0.f;
#pragma unroll 8
        for (int qd = 0; qd < 32; ++qd) {
            uint4 vv = vrow[qd];          // pairs mp = 4qd..4qd+3 for o=j
            uint4 pp = p4[qd];            // broadcast
            racc = FDOT2(bch(pp.x), bch(vv.x), racc);
            racc = FDOT2(bch(pp.y), bch(vv.y), racc);
            racc = FDOT2(bch(pp.z), bch(vv.z), racc);
            racc = FDOT2(bch(pp.w), bch(vv.w), racc);
        }
        float ret = racc * inv;

        // ---- R matvec: ret packed like h (pairs via shfl); WR in regs ----
        float rx = __shfl_xor(ret, 1);
        unsigned rpu = packpair(ret, rx, odd);
        float Rr = 0.f, Rz = 0.f, Rn = 0.f;
#pragma unroll
        for (int k2 = 0; k2 < 32; ++k2) {
            h2v rr = bch(rl_u(rpu, 2*k2));
            Rr = FDOT2(rr, rr2[k2], Rr);
            Rz = FDOT2(rr, rz2[k2], Rz);
            Rn = FDOT2(rr, rn2[k2], Rn);
        }
        const float RrB = Rr + bhr, RzB = Rz + bhz;

        // ---- 16 GRU steps: 4 dynamic groups x 4 unrolled (I-cache OK).
        //      Tokens come from the hoisted regs via cndmask select. ----
#pragma unroll 1
        for (int g = 0; g < 4; ++g) {
            const bool gb1 = (g & 1), gb2 = (g & 2);
            int4 tlo, thi, tg;
            tlo.x = gb1 ? pB.x : pA.x; tlo.y = gb1 ? pB.y : pA.y;
            tlo.z = gb1 ? pB.z : pA.z; tlo.w = gb1 ? pB.w : pA.w;
            thi.x = gb1 ? pD.x : pC.x; thi.y = gb1 ? pD.y : pC.y;
            thi.z = gb1 ? pD.z : pC.z; thi.w = gb1 ? pD.w : pC.w;
            tg.x = gb2 ? thi.x : tlo.x; tg.y = gb2 ? thi.y : tlo.y;
            tg.z = gb2 ? thi.z : tlo.z; tg.w = gb2 ? thi.w : tlo.w;
            const float* GA = G + tg.x*192;
            const float* GB = G + tg.y*192;
            const float* GC = G + tg.z*192;
            const float* GD = G + tg.w*192;
            float gA0 = GA[j], gA1 = GA[64+j], gA2 = GA[128+j];
            float gB0 = GB[j], gB1 = GB[64+j], gB2 = GB[128+j];
            float gC0 = GC[j], gC1 = GC[64+j], gC2 = GC[128+j];
            float gD0 = GD[j], gD1 = GD[64+j], gD2 = GD[128+j];

            GRU_STEP(gA0, gA1, gA2);
            GRU_STEP(gB0, gB1, gB2);
            GRU_STEP(gC0, gC1, gC2);
            GRU_STEP(gD0, gD1, gD2);
        }
    }

    // ---- head: out[b][j] = head_b[j] + sum_k h[k]*head_w[j][k] (fp32) ----
    float o = head_b[j];
#pragma unroll
    for (int k4 = 0; k4 < 16; ++k4) {
        float h0 = rl(h, 4*k4+0), h1 = rl(h, 4*k4+1);
        float h2 = rl(h, 4*k4+2), h3 = rl(h, 4*k4+3);
        const float* hw = head_w + j*64 + 4*k4;
        o += h0*hw[0] + h1*hw[1] + h2*hw[2] + h3*hw[3];
    }
    out[(size_t)b*64 + j] = o;
}

extern "C" void kernel_launch(void* const* d_in, const int* in_sizes, int n_in,
                              void* d_out, int out_size, void* d_ws, size_t ws_size,
                              hipStream_t stream) {
    const int*   seq      = (const int*)  d_in[0];
    const float* memory   = (const float*)d_in[1];
    const float* embed_w  = (const float*)d_in[2];
    const float* w_ih     = (const float*)d_in[3];
    const float* w_hh     = (const float*)d_in[4];
    const float* b_ih     = (const float*)d_in[5];
    const float* b_hh     = (const float*)d_in[6];
    const float* key_w    = (const float*)d_in[7];
    const float* key_b    = (const float*)d_in[8];
    const float* val_w    = (const float*)d_in[9];
    const float* val_b    = (const float*)d_in[10];
    const float* query_w  = (const float*)d_in[11];
    const float* query_b  = (const float*)d_in[12];
    const float* head_w   = (const float*)d_in[13];
    const float* head_b   = (const float*)d_in[14];

    char* ws = (char*)d_ws;
    unsigned* kT2  = (unsigned*)(ws + WS_KT);
    unsigned* vT2  = (unsigned*)(ws + WS_V);
    float*    G    = (float*)   (ws + WS_G);
    unsigned* WPhh2 = (unsigned*)(ws + WS_WPHH);
    unsigned* WR2p  = (unsigned*)(ws + WS_WR);
    unsigned* QP2   = (unsigned*)(ws + WS_QP);
    float4*   KWP   = (float4*)  (ws + WS_KWP);
    float4*   VWP   = (float4*)  (ws + WS_VWP);

    (void)hipFuncSetAttribute((const void*)recurrent_main,
                              hipFuncAttributeMaxDynamicSharedMemorySize,
                              (int)SMEM_BYTES);

    pack_weights<<<64, 256, 0, stream>>>(w_ih, w_hh, query_w, key_w, val_w,
                                         WPhh2, WR2p, QP2, KWP, VWP);
    build_G<<<64, 64, 0, stream>>>(embed_w, w_ih, b_ih, G);
    compute_kv<<<(B_*M_)/4, 256, 0, stream>>>(memory, key_b, val_b, KWP, VWP, kT2, vT2);
    recurrent_main<<<B_, 64, SMEM_BYTES, stream>>>(seq, b_hh, query_b, head_w, head_b,
                                                   kT2, vT2, G, WPhh2, WR2p, QP2,
                                                   (float*)d_out);
}